// Round 9
// baseline (345.118 us; speedup 1.0000x reference)
//
#include <hip/hip_runtime.h>
#include <stdint.h>

#define NF 8192
#define NX 2048
#define MROWS 8192
#define NGROUPS 32
#define NT 32   // NX/64 K-tiles

typedef unsigned short u16;
typedef __bf16 bf16x8 __attribute__((ext_vector_type(8)));
typedef float f32x4 __attribute__((ext_vector_type(4)));

#define AS1 __attribute__((address_space(1)))
#define AS3 __attribute__((address_space(3)))

// async global->LDS, 16B/lane; LDS dest = wave-uniform base + lane*16.
__device__ __forceinline__ void glds16(const void* g, void* l) {
    __builtin_amdgcn_global_load_lds((AS1 void*)(uintptr_t)g,
                                     (AS3 void*)(uintptr_t)l, 16, 0, 0);
}

__device__ __forceinline__ u16 f2bf(float f) {
    unsigned u = __float_as_uint(f);
    return (u16)((u + 0x7FFFu + ((u >> 16) & 1u)) >> 16);  // RNE
}

// packed [NF, NX/2] (one byte per int32, two nibbles) -> W bf16 [NF, NX] row-major.
__global__ void dequant_kernel(const int* __restrict__ packed,
                               const float* __restrict__ scales,
                               const int* __restrict__ zeros,
                               uint32_t* __restrict__ W2) {
    int tid = blockIdx.x * blockDim.x + threadIdx.x;   // [0, NF*NX/2)
    int f = tid >> 10;          // NX/2 = 1024 per row
    int i = tid & 1023;
    int g = f * NGROUPS + (i >> 5);
    int p = packed[tid];
    float s = scales[g];
    float z = (float)zeros[g];
    float w0 = ((float)(p & 15) - z) * s;
    float w1 = ((float)((p >> 4) & 15) - z) * s;
    W2[tid] = (uint32_t)f2bf(w0) | ((uint32_t)f2bf(w1) << 16);
}

// x fp32 -> bf16 in FRAGMENT-PACKED layout: for A-fragment (mt, kt)
// (16 m-rows x 32 k), lane = quad*16+l15 holds x[mt*16+l15][kt*32+quad*8 .. +8];
// stored at Xb + (mt*64 + kt)*1024 + lane*16 bytes.  The gemm then loads A
// fragments global->VGPR as fully-coalesced 1KB b128 wave-loads (no LDS).
__global__ void cvt_kernel(const float* __restrict__ x, u16* __restrict__ y) {
    const int tid = blockIdx.x * blockDim.x + threadIdx.x;
    const int wid = tid >> 6;            // 0..32767 = mt*64 + kt
    const int lane = tid & 63;
    const int l15 = lane & 15;
    const int quad = lane >> 4;
    const int m = (wid >> 6) * 16 + l15;
    const int k = (wid & 63) * 32 + quad * 8;
    const float4* src = (const float4*)(x + (size_t)m * NX + k);
    float4 v0 = src[0], v1 = src[1];
    ushort4 lo, hi;
    lo.x = f2bf(v0.x); lo.y = f2bf(v0.y); lo.z = f2bf(v0.z); lo.w = f2bf(v0.w);
    hi.x = f2bf(v1.x); hi.y = f2bf(v1.y); hi.z = f2bf(v1.z); hi.w = f2bf(v1.w);
    ushort4* dst = (ushort4*)((char*)y + (size_t)wid * 1024 + lane * 16);
    dst[0] = lo; dst[1] = hi;
}

// ===========================================================================
// 128x128 tile, 4 waves (2Mx2N, 64x64/wave), BK=64, mfma_f32_16x16x32_bf16.
// R6 structure (the only one measured to pipeline: wall ~= 1.1x LDS work)
// with the A path REMOVED from LDS:
//   - A: direct global->VGPR from fragment-packed Xb, 8 coalesced b128
//        loads/wave/tile, prefetched 1 tile ahead, gated by counted vmcnt.
//   - B: R6's proven LDS path verbatim (dbuf 2 x 16 KiB, zero-conflict
//        swizzle, 4 glds/tile, LGKM4/LGKM0 bank split).
// Per pair-tile (2 blocks/CU): LDS 96 KB (~1129 cyc) vs R6's 192 KB (2259);
// MFMA 1242 cyc -> MFMA-bound.  A-VMEM 64 KB rides the separate vector-mem
// pipe (L1/L2-resident panel, wn-wave pairs read identical fragments).
//
// vmcnt ledger (steady state, per wave, order: 4 glds then 8 a-loads/tile):
//   enter tile T:        outstanding =  8   (a(T), issued at T-1)
//   after issue:         outstanding = 20   (a(T) + glds B(T+1) + a(T+1))
//   VMCNT12 before MFMA: drains a(T) oldest-8 -> a(T) in regs
//   VMCNT8 at tile end:  drains glds B(T+1)   -> BAR@T+1 publishes LDS
// Tail: T=31 issues nothing -> VMCNT0 before MFMA, no end-wait.
// B-dbuf hazards: exactly R6's (WAR: so's readers LGKM0-drained pre-BAR;
// RAW: per-wave VMCNT8 then BAR).
// Register banks aA/aB ping-pong via 2x-unrolled body (rule #20: no
// runtime-indexed frag arrays).
// ===========================================================================

#define BAR     __builtin_amdgcn_s_barrier()
#define LGKM4   asm volatile("s_waitcnt lgkmcnt(4)" ::: "memory")
#define LGKM0   asm volatile("s_waitcnt lgkmcnt(0)" ::: "memory")
#define VMCNT12 asm volatile("s_waitcnt vmcnt(12)" ::: "memory")
#define VMCNT8  asm volatile("s_waitcnt vmcnt(8)" ::: "memory")
#define VMCNT0  asm volatile("s_waitcnt vmcnt(0)" ::: "memory")
#define FENCE   __builtin_amdgcn_sched_barrier(0)

#define LD8(off) (*(const bf16x8*)(smem + (off)))

#define STAGEB(BUF, T_) do { \
    const char* _sb = srcB + (size_t)(T_) * 128; \
    glds16(_sb,          smem + (BUF) + t16); \
    glds16(_sb + 131072, smem + (BUF) + 4096  + t16); \
    glds16(_sb + 262144, smem + (BUF) + 8192  + t16); \
    glds16(_sb + 393216, smem + (BUF) + 12288 + t16); \
} while (0)

#define TILE(T_, AC, AN) do { \
    const int bo = ((T_) & 1) << 14; \
    const int so = bo ^ 16384; \
    FENCE; BAR; FENCE; \
    _Pragma("unroll") \
    for (int j_ = 0; j_ < 4; ++j_) b0[j_] = LD8(bo + bOff + j_ * 2048 + sx0); \
    _Pragma("unroll") \
    for (int j_ = 0; j_ < 4; ++j_) b1[j_] = LD8(bo + bOff + j_ * 2048 + sx1); \
    FENCE; \
    if ((T_) + 1 < NT) { \
        STAGEB(so, (T_) + 1); \
        _Pragma("unroll") \
        for (int i_ = 0; i_ < 8; ++i_) \
            AN[i_] = *(const bf16x8*)(aBase + (i_ >> 1) * 65536 + \
                                      ((T_) + 1) * 2048 + (i_ & 1) * 1024); \
    } \
    FENCE; LGKM4; \
    if ((T_) + 1 < NT) { VMCNT12; } else { VMCNT0; } \
    FENCE; \
    __builtin_amdgcn_s_setprio(1); \
    _Pragma("unroll") \
    for (int i_ = 0; i_ < 4; ++i_) \
        _Pragma("unroll") \
        for (int j_ = 0; j_ < 4; ++j_) \
            acc[i_][j_] = __builtin_amdgcn_mfma_f32_16x16x32_bf16(AC[2 * i_], b0[j_], acc[i_][j_], 0, 0, 0); \
    __builtin_amdgcn_s_setprio(0); \
    FENCE; LGKM0; FENCE; \
    __builtin_amdgcn_s_setprio(1); \
    _Pragma("unroll") \
    for (int i_ = 0; i_ < 4; ++i_) \
        _Pragma("unroll") \
        for (int j_ = 0; j_ < 4; ++j_) \
            acc[i_][j_] = __builtin_amdgcn_mfma_f32_16x16x32_bf16(AC[2 * i_ + 1], b1[j_], acc[i_][j_], 0, 0, 0); \
    __builtin_amdgcn_s_setprio(0); \
    FENCE; \
    if ((T_) + 1 < NT) VMCNT8; \
} while (0)

__global__ __launch_bounds__(256, 2)
void gemm_kernel(const u16* __restrict__ A /*frag-packed Xb*/,
                 const u16* __restrict__ B /*W row-major*/,
                 const float* __restrict__ bias, float* __restrict__ C) {
    __shared__ __align__(16) char smem[32768];   // B dbuf: 2 x 16 KiB

    const int t = threadIdx.x;

    // T1: striped XCD swizzle (R6 geometry). Grid 4096 = 64 by x 64 bx;
    // each XCD owns 8 by-rows as 4 supers of (2 by x 64 bx), by fastest.
    const int bid = blockIdx.x;
    const int xcd = bid & 7;
    const int local = bid >> 3;          // 0..511
    const int super = local >> 7;        // 0..3
    const int r = local & 127;
    const int by = xcd * 8 + super * 2 + (r & 1);   // 0..63
    const int bx = r >> 1;                          // 0..63
    const int rowA0 = by * 128;
    const int rowB0 = bx * 128;

    // ---- B staging addressing (R6 verbatim: inverse-swizzled source) ----
    const int t16 = t * 16;
    const int ulog = (t & 7) ^ ((t >> 3) & 7);
    const int koffB = (ulog >> 2) * 64 + (ulog & 3) * 16;
    const char* srcB = (const char*)B + (size_t)(rowB0 + (t >> 3)) * 4096 + koffB;

    // ---- fragment addressing ----
    const int lane = t & 63;
    const int wv = t >> 6;
    const int wm = wv >> 1;            // 0..1 (M half, 64 rows)
    const int wn = wv & 1;             // 0..1 (N half, 64 cols)
    const int l15 = lane & 15;
    const int quad = lane >> 4;
    const int l7 = l15 & 7;
    const int sx0 = (quad ^ l7) << 4;        // B kk=0 unit (R6 zero-conflict form)
    const int sx1 = ((4 + quad) ^ l7) << 4;  // B kk=1 unit
    const int bOff = (wn * 64 + l15) * 128;

    // A: frag-packed Xb; wave wm covers mt = by*8 + wm*4 + i (i=0..3)
    const char* aBase = (const char*)A + ((size_t)(by * 8 + wm * 4) << 16) + lane * 16;

    f32x4 acc[4][4];
#pragma unroll
    for (int i = 0; i < 4; ++i)
#pragma unroll
        for (int j = 0; j < 4; ++j) acc[i][j] = {0.f, 0.f, 0.f, 0.f};

    bf16x8 aA[8], aB_[8], b0[4], b1[4];

    // ---- prologue: stage B(0)->buf0 (4 glds); load a(0) (8); drain glds ----
    STAGEB(0, 0);
#pragma unroll
    for (int i = 0; i < 8; ++i)
        aA[i] = *(const bf16x8*)(aBase + (i >> 1) * 65536 + (i & 1) * 1024);
    VMCNT8;   // glds B(0) done (own); a(0) stays in flight; BAR publishes

#pragma unroll 1
    for (int T = 0; T < NT; T += 2) {
        TILE(T,     aA,  aB_);
        TILE(T + 1, aB_, aA);
    }

    // ---- epilogue: C/D col = l15, row = quad*4 + e (m89/m91) ----
    const int col0 = rowB0 + wn * 64 + l15;
    const int row0 = rowA0 + wm * 64 + quad * 4;
    float bj[4];
#pragma unroll
    for (int j = 0; j < 4; ++j) bj[j] = bias[col0 + j * 16];
#pragma unroll
    for (int i = 0; i < 4; ++i) {
#pragma unroll
        for (int e = 0; e < 4; ++e) {
            float* crow = C + (size_t)(row0 + i * 16 + e) * NF;
#pragma unroll
            for (int j = 0; j < 4; ++j)
                __builtin_nontemporal_store(acc[i][j][e] + bj[j], crow + col0 + j * 16);
        }
    }
}

extern "C" void kernel_launch(void* const* d_in, const int* in_sizes, int n_in,
                              void* d_out, int out_size, void* d_ws, size_t ws_size,
                              hipStream_t stream) {
    const float* x      = (const float*)d_in[0];   // [4,2048,2048] fp32
    const int* packed   = (const int*)d_in[1];     // [8192,1024]
    const float* scales = (const float*)d_in[2];   // [8192,32]
    const int* zeros    = (const int*)d_in[3];     // [8192,32]
    const float* bias   = (const float*)d_in[4];   // [8192]
    float* out = (float*)d_out;                    // [8192, 8192] fp32

    // workspace: W bf16 (32 MiB) + Xb frag-packed bf16 (32 MiB)
    u16* Wq = (u16*)d_ws;
    u16* Xb = Wq + (size_t)NF * NX;

    dequant_kernel<<<(NF * (NX / 2)) / 256, 256, 0, stream>>>(packed, scales, zeros, (uint32_t*)Wq);
    cvt_kernel<<<(MROWS / 16) * (NX / 32) * 64 / 256, 256, 0, stream>>>(x, Xb);

    gemm_kernel<<<dim3((MROWS / 128) * (NF / 128)), 256, 0, stream>>>(Xb, Wq, bias, out);
}

// Round 10
// 284.544 us; speedup vs baseline: 1.2129x; 1.2129x over previous
//
#include <hip/hip_runtime.h>
#include <stdint.h>

#define NF 8192
#define NX 2048
#define MROWS 8192
#define NGROUPS 32
#define NT 32   // NX/64 K-tiles

typedef unsigned short u16;
typedef __bf16 bf16x8 __attribute__((ext_vector_type(8)));
typedef float f32x4 __attribute__((ext_vector_type(4)));

#define AS1 __attribute__((address_space(1)))
#define AS3 __attribute__((address_space(3)))

// async global->LDS, 16B/lane; LDS dest = wave-uniform base + lane*16.
__device__ __forceinline__ void glds16(const void* g, void* l) {
    __builtin_amdgcn_global_load_lds((AS1 void*)(uintptr_t)g,
                                     (AS3 void*)(uintptr_t)l, 16, 0, 0);
}

__device__ __forceinline__ u16 f2bf(float f) {
    unsigned u = __float_as_uint(f);
    return (u16)((u + 0x7FFFu + ((u >> 16) & 1u)) >> 16);  // RNE
}

// packed [NF, NX/2] (one byte per int32, two nibbles) -> W bf16 [NF, NX] row-major.
__global__ void dequant_kernel(const int* __restrict__ packed,
                               const float* __restrict__ scales,
                               const int* __restrict__ zeros,
                               uint32_t* __restrict__ W2) {
    int tid = blockIdx.x * blockDim.x + threadIdx.x;   // [0, NF*NX/2)
    int f = tid >> 10;          // NX/2 = 1024 per row
    int i = tid & 1023;
    int g = f * NGROUPS + (i >> 5);
    int p = packed[tid];
    float s = scales[g];
    float z = (float)zeros[g];
    float w0 = ((float)(p & 15) - z) * s;
    float w1 = ((float)((p >> 4) & 15) - z) * s;
    W2[tid] = (uint32_t)f2bf(w0) | ((uint32_t)f2bf(w1) << 16);
}

// x fp32 -> bf16, 4 elems/thread
__global__ void cvt_kernel(const float4* __restrict__ x, ushort4* __restrict__ y) {
    int i = blockIdx.x * blockDim.x + threadIdx.x;
    float4 v = x[i];
    ushort4 o;
    o.x = f2bf(v.x); o.y = f2bf(v.y); o.z = f2bf(v.z); o.w = f2bf(v.w);
    y[i] = o;
}

// ===========================================================================
// 256x256 tile, 8 waves (2Mx4N, wave tile 128x64), BK=64,
// mfma_f32_16x16x32_bf16, ONE block/CU (LDS dbuf 2 x 64 KiB = 128 KiB).
// R6's schedule applied to the 256^2 tile: ONE barrier + one vmcnt(0) per
// K-tile; lgkm-split gating so MFMA k0 runs while k1's reads complete.
// LDS bytes per output elem: 4 B (vs R6's 6) -- R6 measured LDS-byte-bound
// at 91% pipe efficiency, so bytes/output is the lever.  Overlap source:
// intra-block wave drift within the barrier interval (8 waves, 2/SIMD).
//
// LDS buffer (64 KiB): A at +0 (256 lines), B at +32768 (256 lines).
// Line = 128 B = one row's BK=64 bf16, 8 x 16B units (R6's exact geometry,
// measured ZERO conflicts in R1/R6/R7/R8):
//   content(line, phys u) = k-unit u ^ (line&7); k-byte(u) = (u>>2)*64+(u&3)*16.
//   write: glds linear, unit U = t + 512c: line = (t>>3)+64c, phys = t&7;
//          source k-unit ulog = (t&7)^((t>>3)&7), row = (t>>3)+64c.
//   read:  line = base + i*16 + l15 (base % 16 == 0), phys = (kk*4+quad)^(l15&7)
//          -> 16-lane-period form; lanes hit distinct banks.
//
// Per K-tile T (bo active, so inactive):
//   BAR                       // T's stages visible (own vmcnt0 at T-1 + BAR)
//   issue a0[8],b0[4] (kk0); 8 glds stage(T+1)->so; issue a1[8] (kk1)
//     WAR on so: its readers (T-1) lgkm-drained before their MFMA, pre-BAR.
//   LGKM8  -> oldest 12 DS (a0,b0) done; MFMA k0 j=0,1 (16)
//   issue b1[4] (kk1); MFMA k0 j=2,3 (16)    [caps peak frag liveness]
//   LGKM0  -> a1,b1 done; MFMA k1 (32)
//   VMCNT0 // own 8 stages for T+1 landed (had the whole tile to fly)
// ===========================================================================

#define BAR    __builtin_amdgcn_s_barrier()
#define LGKM8  asm volatile("s_waitcnt lgkmcnt(8)" ::: "memory")
#define LGKM0  asm volatile("s_waitcnt lgkmcnt(0)" ::: "memory")
#define VMCNT0 asm volatile("s_waitcnt vmcnt(0)" ::: "memory")
#define FENCE  __builtin_amdgcn_sched_barrier(0)

#define LD8(off) (*(const bf16x8*)(smem + (off)))

#define MFMA(d, va, vb) d = __builtin_amdgcn_mfma_f32_16x16x32_bf16(va, vb, d, 0, 0, 0)

// 8 glds/thread: A 4 chunks of 64 rows, then B 4 chunks (chunk stride 64*4096B)
#define STAGE8(BUF, KOFF) do { \
    glds16(srcA + (KOFF),          smem + (BUF) + t16); \
    glds16(srcA + 262144 + (KOFF), smem + (BUF) + 8192  + t16); \
    glds16(srcA + 524288 + (KOFF), smem + (BUF) + 16384 + t16); \
    glds16(srcA + 786432 + (KOFF), smem + (BUF) + 24576 + t16); \
    glds16(srcB + (KOFF),          smem + (BUF) + 32768 + t16); \
    glds16(srcB + 262144 + (KOFF), smem + (BUF) + 40960 + t16); \
    glds16(srcB + 524288 + (KOFF), smem + (BUF) + 49152 + t16); \
    glds16(srcB + 786432 + (KOFF), smem + (BUF) + 57344 + t16); \
} while (0)

__global__ __launch_bounds__(512, 2)
void gemm_kernel(const u16* __restrict__ A, const u16* __restrict__ B,
                 const float* __restrict__ bias, float* __restrict__ C) {
    __shared__ __align__(16) char smem[131072];   // 2 x 64 KiB dbuf

    const int t = threadIdx.x;

    // T1: striped XCD swizzle. Grid 1024 = 32 by x 32 bx; each XCD owns
    // 4 by-rows as 2 supers of (2 by x 32 bx), by fastest.
    const int bid = blockIdx.x;
    const int xcd = bid & 7;
    const int local = bid >> 3;          // 0..127
    const int super = local >> 6;        // 0..1
    const int r = local & 63;
    const int by = xcd * 4 + super * 2 + (r & 1);   // 0..31
    const int bx = r >> 1;                          // 0..31
    const int rowA0 = by * 256;
    const int rowB0 = bx * 256;

    // ---- staging addressing (inverse-swizzled global source, linear LDS) ----
    const int t16 = t * 16;
    const int ulog = (t & 7) ^ ((t >> 3) & 7);
    const int koffS = (ulog >> 2) * 64 + (ulog & 3) * 16;
    const char* srcA = (const char*)A + (size_t)(rowA0 + (t >> 3)) * 4096 + koffS;
    const char* srcB = (const char*)B + (size_t)(rowB0 + (t >> 3)) * 4096 + koffS;

    // ---- fragment read addressing (16-lane-period zero-conflict form) ----
    const int lane = t & 63;
    const int wv = t >> 6;
    const int wm = wv >> 2;            // 0..1 (M half, 128 rows)
    const int wn = wv & 3;             // 0..3 (N quarter, 64 cols)
    const int l15 = lane & 15;
    const int quad = lane >> 4;
    const int l7 = l15 & 7;
    const int sx0 = (quad ^ l7) << 4;        // kk=0 unit
    const int sx1 = ((4 + quad) ^ l7) << 4;  // kk=1 unit
    const int aOff = (wm * 128 + l15) * 128;           // + i*2048
    const int bOff = 32768 + (wn * 64 + l15) * 128;    // + j*2048

    f32x4 acc[8][4];
#pragma unroll
    for (int i = 0; i < 8; ++i)
#pragma unroll
        for (int j = 0; j < 4; ++j) acc[i][j] = {0.f, 0.f, 0.f, 0.f};

    bf16x8 a0[8], a1[8], b0[4], b1[4];

    // ---- prologue: stage tile0 -> buf0; own-drain; BAR at loop top ----
    STAGE8(0, 0);
    VMCNT0;

#pragma unroll 1
    for (int T = 0; T < NT; ++T) {
        const int bo = (T & 1) << 16;   // active buffer
        const int so = bo ^ 65536;      // inactive (receives T+1)

        FENCE; BAR; FENCE;
        // kk0 reads (12 DS)
#pragma unroll
        for (int i = 0; i < 8; ++i) a0[i] = LD8(bo + aOff + i * 2048 + sx0);
#pragma unroll
        for (int j = 0; j < 4; ++j) b0[j] = LD8(bo + bOff + j * 2048 + sx0);
        FENCE;
        if (T + 1 < NT) STAGE8(so, (T + 1) * 128);   // vmcnt-side; WAR-safe post-BAR
        FENCE;
        // kk1 A reads (8 DS)
#pragma unroll
        for (int i = 0; i < 8; ++i) a1[i] = LD8(bo + aOff + i * 2048 + sx1);
        FENCE; LGKM8; FENCE;            // a0,b0 ready (oldest 12 of 20)
        __builtin_amdgcn_s_setprio(1);
#pragma unroll
        for (int j = 0; j < 2; ++j)
#pragma unroll
            for (int i = 0; i < 8; ++i) MFMA(acc[i][j], a0[i], b0[j]);
        __builtin_amdgcn_s_setprio(0);
        FENCE;
        // kk1 B reads (4 DS) -- issued late to cap frag liveness
#pragma unroll
        for (int j = 0; j < 4; ++j) b1[j] = LD8(bo + bOff + j * 2048 + sx1);
        FENCE;
        __builtin_amdgcn_s_setprio(1);
#pragma unroll
        for (int j = 2; j < 4; ++j)
#pragma unroll
            for (int i = 0; i < 8; ++i) MFMA(acc[i][j], a0[i], b0[j]);
        __builtin_amdgcn_s_setprio(0);
        FENCE; LGKM0; FENCE;            // a1,b1 ready (hid under k0 MFMAs)
        __builtin_amdgcn_s_setprio(1);
#pragma unroll
        for (int j = 0; j < 4; ++j)
#pragma unroll
            for (int i = 0; i < 8; ++i) MFMA(acc[i][j], a1[i], b1[j]);
        __builtin_amdgcn_s_setprio(0);
        FENCE;
        if (T + 1 < NT) VMCNT0;         // own 8 stages for T+1 landed
    }

    // ---- epilogue: C/D col = l15, row = quad*4 + e (m89/m91) ----
    const int col0 = rowB0 + wn * 64 + l15;
    const int row0 = rowA0 + wm * 128 + quad * 4;
    float bj[4];
#pragma unroll
    for (int j = 0; j < 4; ++j) bj[j] = bias[col0 + j * 16];
#pragma unroll
    for (int i = 0; i < 8; ++i) {
#pragma unroll
        for (int e = 0; e < 4; ++e) {
            float* crow = C + (size_t)(row0 + i * 16 + e) * NF;
#pragma unroll
            for (int j = 0; j < 4; ++j)
                __builtin_nontemporal_store(acc[i][j][e] + bj[j], crow + col0 + j * 16);
        }
    }
}

extern "C" void kernel_launch(void* const* d_in, const int* in_sizes, int n_in,
                              void* d_out, int out_size, void* d_ws, size_t ws_size,
                              hipStream_t stream) {
    const float* x      = (const float*)d_in[0];   // [4,2048,2048] fp32
    const int* packed   = (const int*)d_in[1];     // [8192,1024]
    const float* scales = (const float*)d_in[2];   // [8192,32]
    const int* zeros    = (const int*)d_in[3];     // [8192,32]
    const float* bias   = (const float*)d_in[4];   // [8192]
    float* out = (float*)d_out;                    // [8192, 8192] fp32

    // workspace: W bf16 (32 MiB) + x bf16 (32 MiB); fully rewritten every call
    u16* Wq = (u16*)d_ws;
    u16* Xb = Wq + (size_t)NF * NX;

    dequant_kernel<<<(NF * (NX / 2)) / 256, 256, 0, stream>>>(packed, scales, zeros, (uint32_t*)Wq);
    cvt_kernel<<<(MROWS * NX / 4) / 256, 256, 0, stream>>>((const float4*)x, (ushort4*)Xb);

    gemm_kernel<<<dim3((MROWS / 256) * (NF / 256)), 512, 0, stream>>>(Xb, Wq, bias, out);
}